// Round 5
// baseline (305.196 us; speedup 1.0000x reference)
//
#include <hip/hip_runtime.h>
#include <hip/hip_bf16.h>
#include <cstdint>
#include <cstddef>

// ---------------------------------------------------------------- constants
#define IN_CH   128
#define OUT_CH  64
#define CAT_CH  192   // IN_CH + OUT_CH

typedef short bf16x8 __attribute__((ext_vector_type(8)));
typedef float f32x4  __attribute__((ext_vector_type(4)));
typedef unsigned long long u64;
typedef unsigned int u32;

__device__ __forceinline__ float sigmoidf_(float x) { return 1.f / (1.f + __expf(-x)); }

// fp32 -> bf16 (RNE)
__device__ __forceinline__ unsigned short f2bf(float f) {
    u32 u = __float_as_uint(f);
    u32 r = (u + 0x7fffu + ((u >> 16) & 1u)) >> 16;
    return (unsigned short)r;
}
__device__ __forceinline__ float bflo(u32 v) { return __uint_as_float(v << 16); }
__device__ __forceinline__ float bfhi(u32 v) { return __uint_as_float(v & 0xffff0000u); }

// ---------------------------------------------------------------- dtype detect
// edge_index may be int64 (declared) or int32 (JAX x64 off). For int64 data of
// values < 2^31, every odd 32-bit word is zero.
__global__ void detect_kernel(const unsigned int* __restrict__ ei, int* __restrict__ flag) {
    unsigned int v = ei[(threadIdx.x << 1) + 1];
    unsigned long long b = __ballot(v != 0u);
    if (threadIdx.x == 0) *flag = (b != 0ull) ? 1 : 0;   // 1 => int32 layout
}

__device__ __forceinline__ int load_col(const void* ei, int i, int E, int f) {
    return f ? ((const int*)ei)[E + i] : (int)((const long long*)ei)[E + i];
}
__device__ __forceinline__ int load_row(const void* ei, int i, int E, int f) {
    return f ? ((const int*)ei)[i] : (int)((const long long*)ei)[i];
}

// ---------------------------------------------------------------- preprocessing
// one u64 atomic per edge: high32 = count, low32 = sum(w) in 2^-20 fixed point.
// Returned old count == this edge's rank within its destination bucket.
// 4 edges/thread for atomic-latency ILP.
__global__ void hist2_kernel(const void* __restrict__ ei, const float* __restrict__ w,
                             u64* __restrict__ packed, u32* __restrict__ rank,
                             const int* __restrict__ flag, int E) {
    int i0 = (blockIdx.x * blockDim.x + threadIdx.x) * 4;
    if (i0 >= E) return;
    int f = *flag;
    u32 rk[4];
#pragma unroll
    for (int k = 0; k < 4; k++) {
        int i = i0 + k;
        if (i < E) {
            int c = load_col(ei, i, E, f);
            u32 wq = __float2uint_rn(w[i] * 1048576.0f);     // 2^20 scale
            u64 old = atomicAdd(&packed[c], (1ull << 32) | (u64)wq);
            rk[k] = (u32)(old >> 32);
        }
    }
#pragma unroll
    for (int k = 0; k < 4; k++)
        if (i0 + k < E) rank[i0 + k] = rk[k];
}

// ---------------------------------------------------------------- scan (3-phase)
// scan1 fused with dinv/count unpack from the packed histogram.
__global__ __launch_bounds__(256) void scan1_kernel(const u64* __restrict__ packed,
                                                    float* __restrict__ dinv,
                                                    int* __restrict__ starts,
                                                    int* __restrict__ bsum, int n) {
    __shared__ int s[256];
    int i = blockIdx.x * 256 + threadIdx.x;
    int v = 0;
    if (i < n) {
        u64 p = packed[i];
        float wsum = (float)(u32)(p & 0xffffffffull) * (1.0f / 1048576.0f);
        dinv[i] = rsqrtf(1.0f + wsum);                   // self-loop weight 1 => deg >= 1
        v = (int)(p >> 32);
    }
    s[threadIdx.x] = v;
    __syncthreads();
#pragma unroll
    for (int d = 1; d < 256; d <<= 1) {
        int t = (threadIdx.x >= d) ? s[threadIdx.x - d] : 0;
        __syncthreads();
        s[threadIdx.x] += t;
        __syncthreads();
    }
    if (i < n) starts[i] = s[threadIdx.x] - v;   // exclusive
    if (threadIdx.x == 255) bsum[blockIdx.x] = s[255];
}

__global__ __launch_bounds__(256) void scan2_kernel(int* __restrict__ bsum, int nb) {
    __shared__ int s[256];
    int t = threadIdx.x;
    int v = (t < nb) ? bsum[t] : 0;
    s[t] = v;
    __syncthreads();
#pragma unroll
    for (int d = 1; d < 256; d <<= 1) {
        int u = (t >= d) ? s[t - d] : 0;
        __syncthreads();
        s[t] += u;
        __syncthreads();
    }
    if (t < nb) bsum[t] = s[t] - v;   // exclusive block offsets, in place
}

__global__ void scan3_kernel(int* __restrict__ starts, const int* __restrict__ boff,
                             int n, int E) {
    int i = blockIdx.x * blockDim.x + threadIdx.x;
    if (i == 0) starts[n] = E;   // sentinel
    if (i < n) starts[i] += boff[blockIdx.x];
}

// ---------------------------------------------------------------- CSR scatter (atomic-free)
// pairs[pos] = {src (low32), norm (high32)} grouped by destination.
// 4 edges/thread for load-chain ILP.
__global__ void scatter2_kernel(const void* __restrict__ ei, const float* __restrict__ w,
                                const float* __restrict__ dinv, const int* __restrict__ starts,
                                const u32* __restrict__ rank, u64* __restrict__ pairs,
                                const int* __restrict__ flag, int E) {
    int i0 = (blockIdx.x * blockDim.x + threadIdx.x) * 4;
    if (i0 >= E) return;
    int f = *flag;
    int r[4], c[4];
#pragma unroll
    for (int k = 0; k < 4; k++) {
        int i = i0 + k;
        if (i < E) { r[k] = load_row(ei, i, E, f); c[k] = load_col(ei, i, E, f); }
    }
#pragma unroll
    for (int k = 0; k < 4; k++) {
        int i = i0 + k;
        if (i < E) {
            float nm = dinv[r[k]] * w[i] * dinv[c[k]];
            int pos = starts[c[k]] + (int)rank[i];
            pairs[pos] = ((u64)__float_as_uint(nm) << 32) | (u32)r[k];
        }
    }
}

// ---------------------------------------------------------------- fp32 -> bf16 convert
__global__ void cvt_kernel(const float* __restrict__ x, const float* __restrict__ hidden,
                           unsigned short* __restrict__ xb, unsigned short* __restrict__ hb,
                           int nx, int nh) {
    int i4 = (blockIdx.x * blockDim.x + threadIdx.x) * 4;
    if (i4 < nx) {
        float4 v = *(const float4*)&x[i4];
        ushort4 o = { f2bf(v.x), f2bf(v.y), f2bf(v.z), f2bf(v.w) };
        *(ushort4*)&xb[i4] = o;
    } else {
        int j = i4 - nx;
        if (j < nh) {
            float4 v = *(const float4*)&hidden[j];
            ushort4 o = { f2bf(v.x), f2bf(v.y), f2bf(v.z), f2bf(v.w) };
            *(ushort4*)&hb[j] = o;
        }
    }
}

// ---------------------------------------------------------------- weight pack (k-major bf16)
__global__ void packW_kernel(const float* __restrict__ Wz, const float* __restrict__ Wr,
                             const float* __restrict__ Wh,
                             unsigned short* __restrict__ Bzrt, unsigned short* __restrict__ Wht) {
    int i = blockIdx.x * blockDim.x + threadIdx.x;
    if (i >= 192 * CAT_CH) return;
    int col = i / CAT_CH, k = i % CAT_CH;
    if (col < 128) {
        float v = (col < 64) ? Wz[k * 64 + col] : Wr[k * 64 + (col - 64)];
        Bzrt[col * CAT_CH + k] = f2bf(v);
    } else {
        Wht[(col - 128) * CAT_CH + k] = f2bf(Wh[k * 64 + (col - 128)]);
    }
}

// ---------------------------------------------------------------- bf16 MFMA GEMM
// C written PLANAR: plane p (=cf) holds cols p*16..p*16+15 as [N][16] bf16.
// 256 threads = 4 waves; block tile 128 rows; wave owns 32 rows x TN cols.
template <int TN>
__global__ __launch_bounds__(256) void gemm_bf16_kernel(
    const unsigned short* __restrict__ A0, int a0w,
    const unsigned short* __restrict__ A1, int a1w,
    const unsigned short* __restrict__ Bt,
    unsigned short* __restrict__ C, int nrows)
{
    __shared__ unsigned short As[128][48];    // 32 k + 16 pad
    __shared__ unsigned short Bs[TN][200];    // 192 k + 8 pad

    const int t = threadIdx.x, lane = t & 63, wave = t >> 6;
    const int rowBase = blockIdx.x * 128;

    for (int idx = t * 8; idx < TN * CAT_CH; idx += 256 * 8) {
        int col = idx / CAT_CH, k = idx % CAT_CH;
        *(int4*)&Bs[col][k] = *(const int4*)&Bt[idx];
    }

    f32x4 acc[2][TN / 16];
#pragma unroll
    for (int rf = 0; rf < 2; rf++)
#pragma unroll
        for (int cf = 0; cf < TN / 16; cf++) acc[rf][cf] = (f32x4){0.f, 0.f, 0.f, 0.f};

    const int srow = t >> 1, half = t & 1;     // A staging: 2 threads/row, 32B each
    int arow = rowBase + srow;
    if (arow >= nrows) arow = nrows - 1;

    for (int k0 = 0; k0 < CAT_CH; k0 += 32) {
        __syncthreads();
        {
            const unsigned short* src = (k0 < a0w)
                ? A0 + (size_t)arow * a0w + k0
                : A1 + (size_t)arow * a1w + (k0 - a0w);
            *(int4*)&As[srow][half * 16] = *(const int4*)(src + half * 16);
            *(int4*)&As[srow][half * 16 + 8] = *(const int4*)(src + half * 16 + 8);
        }
        __syncthreads();

        const int rbase = wave * 32;
        const int koff = (lane >> 4) * 8;
        bf16x8 a0 = *(const bf16x8*)&As[rbase + (lane & 15)][koff];
        bf16x8 a1 = *(const bf16x8*)&As[rbase + 16 + (lane & 15)][koff];
#pragma unroll
        for (int cf = 0; cf < TN / 16; cf++) {
            bf16x8 b = *(const bf16x8*)&Bs[cf * 16 + (lane & 15)][k0 + koff];
            acc[0][cf] = __builtin_amdgcn_mfma_f32_16x16x32_bf16(a0, b, acc[0][cf], 0, 0, 0);
            acc[1][cf] = __builtin_amdgcn_mfma_f32_16x16x32_bf16(a1, b, acc[1][cf], 0, 0, 0);
        }
    }

#pragma unroll
    for (int rf = 0; rf < 2; rf++)
#pragma unroll
        for (int cf = 0; cf < TN / 16; cf++) {
            int row0 = rowBase + wave * 32 + rf * 16 + (lane >> 4) * 4;
#pragma unroll
            for (int r = 0; r < 4; r++) {
                int row = row0 + r;
                if (row < nrows)
                    C[((size_t)cf * nrows + row) * 16 + (lane & 15)] = f2bf(acc[rf][cf][r]);
            }
        }
}

// ---------------------------------------------------------------- SpMM gather core
// Hp: one 16-channel plane [N][16] bf16 (1.6 MB -> fits one XCD L2).
// 8 lanes per edge (sub=lane&7 -> 2 ch each), 8 edge-groups (oct=lane>>3),
// 16 edges per iteration, depth-2 prefetch, shfl-xor reduce over octs.
__device__ __forceinline__ float2 gather_acc(
    const unsigned short* __restrict__ Hp, const u64* __restrict__ pairs,
    int s, int e, int oct, int sub, float ax, float ay)
{
    for (int j = s; j < e; j += 16) {
        u32 hv[2]; float nm[2];
#pragma unroll
        for (int k = 0; k < 2; k++) {
            int jj = j + k * 8 + oct;
            int jc = (jj < e) ? jj : (e - 1);
            u64 p = pairs[jc];
            nm[k] = (jj < e) ? __uint_as_float((u32)(p >> 32)) : 0.f;
            hv[k] = *(const u32*)&Hp[(size_t)(u32)p * 16 + sub * 2];
        }
#pragma unroll
        for (int k = 0; k < 2; k++) {
            ax = fmaf(bflo(hv[k]), nm[k], ax);
            ay = fmaf(bfhi(hv[k]), nm[k], ay);
        }
    }
#pragma unroll
    for (int d = 8; d <= 32; d <<= 1) {
        ax += __shfl_xor(ax, d, 64);
        ay += __shfl_xor(ay, d, 64);
    }
    return make_float2(ax, ay);
}

// z/r aggregation. 8 planes; plane = blockIdx.x & 7 (XCD-pinned on round-robin
// block->XCD dispatch; performance heuristic only). Planes 0-3 = z, 4-7 = r.
__global__ __launch_bounds__(256) void spmm_zr_kernel(
    const unsigned short* __restrict__ H, const u64* __restrict__ pairs,
    const int* __restrict__ starts, const float* __restrict__ dinv,
    const float* __restrict__ hidden, const float* __restrict__ bz,
    const float* __restrict__ br, float* __restrict__ Z,
    unsigned short* __restrict__ RHb, int N)
{
    int bid = blockIdx.x;
    int ck  = bid & 7;
    int node = (bid >> 3) * 4 + (threadIdx.x >> 6);
    if (node >= N) return;
    int lane = threadIdx.x & 63, oct = lane >> 3, sub = lane & 7;

    const unsigned short* Hp = H + (size_t)ck * N * 16;
    int s = starts[node], e = starts[node + 1];
    float d = dinv[node], d2 = d * d;

    u32 self = *(const u32*)&Hp[(size_t)node * 16 + sub * 2];
    float ax = (oct == 0) ? bflo(self) * d2 : 0.f;
    float ay = (oct == 0) ? bfhi(self) * d2 : 0.f;
    float2 a = gather_acc(Hp, pairs, s, e, oct, sub, ax, ay);

    if (oct == 0) {
        if (ck < 4) {
            int c = ck * 16 + sub * 2;
            float2 o = { sigmoidf_(a.x + bz[c]), sigmoidf_(a.y + bz[c + 1]) };
            *(float2*)&Z[(size_t)node * 64 + c] = o;
        } else {
            int c = (ck - 4) * 16 + sub * 2;
            const float* hid = hidden + (size_t)node * 64 + c;
            float rh0 = sigmoidf_(a.x + br[c])     * hid[0];
            float rh1 = sigmoidf_(a.y + br[c + 1]) * hid[1];
            *(u32*)&RHb[(size_t)node * 64 + c] = (u32)f2bf(rh0) | ((u32)f2bf(rh1) << 16);
        }
    }
}

// h-candidate aggregation + tanh/GRU blend. 4 planes; slot = bid&7,
// plane = slot&3 (each plane cached by 2 XCDs), half = slot>>2 picks node group.
__global__ __launch_bounds__(256) void spmm_h_kernel(
    const unsigned short* __restrict__ H, const u64* __restrict__ pairs,
    const int* __restrict__ starts, const float* __restrict__ dinv,
    const float* __restrict__ hidden, const float* __restrict__ bh,
    const float* __restrict__ Z, float* __restrict__ out, int N)
{
    int bid = blockIdx.x;
    int slot = bid & 7;
    int ck = slot & 3, halfg = slot >> 2;
    int node = (bid >> 3) * 8 + halfg * 4 + (threadIdx.x >> 6);
    if (node >= N) return;
    int lane = threadIdx.x & 63, oct = lane >> 3, sub = lane & 7;

    const unsigned short* Hp = H + (size_t)ck * N * 16;
    int s = starts[node], e = starts[node + 1];
    float d = dinv[node], d2 = d * d;

    u32 self = *(const u32*)&Hp[(size_t)node * 16 + sub * 2];
    float ax = (oct == 0) ? bflo(self) * d2 : 0.f;
    float ay = (oct == 0) ? bfhi(self) * d2 : 0.f;
    float2 a = gather_acc(Hp, pairs, s, e, oct, sub, ax, ay);

    if (oct == 0) {
        int c = ck * 16 + sub * 2;
        size_t idx = (size_t)node * 64 + c;
        float2 hid = *(const float2*)&hidden[idx];
        float2 z   = *(const float2*)&Z[idx];
        float hc0 = tanhf(a.x + bh[c]);
        float hc1 = tanhf(a.y + bh[c + 1]);
        float2 o = { z.x * hid.x + (1.f - z.x) * hc0,
                     z.y * hid.y + (1.f - z.y) * hc1 };
        *(float2*)&out[idx] = o;
    }
}

// ---------------------------------------------------------------- launcher
extern "C" void kernel_launch(void* const* d_in, const int* in_sizes, int n_in,
                              void* d_out, int out_size, void* d_ws, size_t ws_size,
                              hipStream_t stream) {
    const float* x      = (const float*)d_in[0];
    const void*  eidx   = d_in[1];
    const float* ew     = (const float*)d_in[2];
    const float* hidden = (const float*)d_in[3];
    const float* Wz     = (const float*)d_in[4];
    const float* bz     = (const float*)d_in[5];
    const float* Wr     = (const float*)d_in[6];
    const float* br     = (const float*)d_in[7];
    const float* Wh     = (const float*)d_in[8];
    const float* bh     = (const float*)d_in[9];
    float* out = (float*)d_out;

    const int E = in_sizes[2];            // 800000
    const int N = in_sizes[3] / OUT_CH;   // 50000

    // workspace carve-up (256B aligned)
    char* base = (char*)d_ws;
    size_t off = 0;
    auto carve = [&](size_t bytes) -> char* {
        char* p = base + off;
        off = (off + bytes + 255) & ~(size_t)255;
        return p;
    };
    u64*   packed = (u64*)  carve((size_t)N * 8);
    u32*   rank   = (u32*)  carve((size_t)E * 4);
    float* dinv   = (float*)carve((size_t)N * 4);
    int*   starts = (int*)  carve((size_t)(N + 1) * 4);
    int*   bsum   = (int*)  carve(256 * 4);
    u64*   pairs  = (u64*)  carve((size_t)E * 8);
    unsigned short* xb   = (unsigned short*)carve((size_t)N * 128 * 2);
    unsigned short* hb   = (unsigned short*)carve((size_t)N * 64 * 2);
    unsigned short* Hzrb = (unsigned short*)carve((size_t)N * 128 * 2);   // 8 planes [N][16]
    unsigned short* RHb  = (unsigned short*)carve((size_t)N * 64 * 2);    // row-major
    unsigned short* Hhb  = (unsigned short*)carve((size_t)N * 64 * 2);    // 4 planes [N][16]
    float* Z = (float*)carve((size_t)N * 64 * 4);
    unsigned short* Bzrt = (unsigned short*)carve((size_t)128 * CAT_CH * 2);
    unsigned short* Wht  = (unsigned short*)carve((size_t)64 * CAT_CH * 2);
    int* flag = (int*)carve(4);
    if (off > ws_size) return;

    const int B256 = 256;
    const int gE4 = (E + 1023) / 1024;        // 4 edges/thread kernels
    const int gN = (N + B256 - 1) / B256;     // scan blocking (<=256 blocks)
    const int gM = (N + 127) / 128;           // GEMM row tiles
    const int gZR = ((N + 3) / 4) * 8;        // (node-group, plane) blocks
    const int gH  = ((N + 7) / 8) * 8;

    // 1. dtype detect
    hipLaunchKernelGGL(detect_kernel, dim3(1), dim3(64), 0, stream,
                       (const unsigned int*)eidx, flag);

    // 2. packed histogram (count | sum w) + per-edge rank
    hipMemsetAsync(packed, 0, (size_t)N * 8, stream);
    hipLaunchKernelGGL(hist2_kernel, dim3(gE4), dim3(B256), 0, stream,
                       eidx, ew, packed, rank, flag, E);

    // 3. exclusive scan -> starts (fused dinv/count unpack)
    hipLaunchKernelGGL(scan1_kernel, dim3(gN), dim3(B256), 0, stream,
                       packed, dinv, starts, bsum, N);
    hipLaunchKernelGGL(scan2_kernel, dim3(1), dim3(B256), 0, stream, bsum, gN);
    hipLaunchKernelGGL(scan3_kernel, dim3(gN), dim3(B256), 0, stream, starts, bsum, N, E);

    // 4. atomic-free CSR scatter
    hipLaunchKernelGGL(scatter2_kernel, dim3(gE4), dim3(B256), 0, stream,
                       eidx, ew, dinv, starts, rank, pairs, flag, E);

    // 5. bf16 conversions + weight packs
    hipLaunchKernelGGL(cvt_kernel, dim3((N * CAT_CH / 4 + 255) / 256), dim3(B256), 0, stream,
                       x, hidden, xb, hb, N * 128, N * 64);
    hipLaunchKernelGGL(packW_kernel, dim3((192 * CAT_CH + 255) / 256), dim3(B256), 0, stream,
                       Wz, Wr, Wh, Bzrt, Wht);

    // 6. GEMM1: Hzrb(planar) = [xb|hb] @ [Wz|Wr]
    hipLaunchKernelGGL((gemm_bf16_kernel<128>), dim3(gM), dim3(B256), 0, stream,
                       xb, 128, hb, 64, Bzrt, Hzrb, N);

    // 7. z/r aggregation (XCD-pinned planes) + sigmoid epilogue -> Z, RHb
    hipLaunchKernelGGL(spmm_zr_kernel, dim3(gZR), dim3(B256), 0, stream,
                       Hzrb, pairs, starts, dinv, hidden, bz, br, Z, RHb, N);

    // 8. GEMM2: Hhb(planar) = [xb|RHb] @ Wh
    hipLaunchKernelGGL((gemm_bf16_kernel<64>), dim3(gM), dim3(B256), 0, stream,
                       xb, 128, RHb, 64, Wht, Hhb, N);

    // 9. h-candidate aggregation + tanh/GRU blend -> out
    hipLaunchKernelGGL(spmm_h_kernel, dim3(gH), dim3(B256), 0, stream,
                       Hhb, pairs, starts, dinv, hidden, bh, Z, out, N);
}

// Round 6
// 200.038 us; speedup vs baseline: 1.5257x; 1.5257x over previous
//
#include <hip/hip_runtime.h>
#include <hip/hip_bf16.h>
#include <cstdint>
#include <cstddef>

// ---------------------------------------------------------------- constants
#define IN_CH   128
#define OUT_CH  64
#define CAT_CH  192   // IN_CH + OUT_CH

typedef short bf16x8 __attribute__((ext_vector_type(8)));
typedef float f32x4  __attribute__((ext_vector_type(4)));
typedef float f32x2  __attribute__((ext_vector_type(2)));
typedef unsigned long long u64;
typedef unsigned int u32;

__device__ __forceinline__ float sigmoidf_(float x) { return 1.f / (1.f + __expf(-x)); }

// fp32 -> bf16 (RNE)
__device__ __forceinline__ unsigned short f2bf(float f) {
    u32 u = __float_as_uint(f);
    u32 r = (u + 0x7fffu + ((u >> 16) & 1u)) >> 16;
    return (unsigned short)r;
}
__device__ __forceinline__ float bflo(u32 v) { return __uint_as_float(v << 16); }
__device__ __forceinline__ float bfhi(u32 v) { return __uint_as_float(v & 0xffff0000u); }
__device__ __forceinline__ float bf1(unsigned short v) { return __uint_as_float((u32)v << 16); }

// fp8 OCP e4m3 (gfx950 native converts)
__device__ __forceinline__ unsigned char f2e4m3(float f) {
    u32 p = __builtin_amdgcn_cvt_pk_fp8_f32(f, f, 0, false);
    return (unsigned char)p;
}
__device__ __forceinline__ f32x2 e4m3x2_to_f(u32 two) {   // 2 fp8 in bits [15:0]
    return __builtin_amdgcn_cvt_pk_f32_fp8(two, false);
}

// ---------------------------------------------------------------- dtype detect
// edge_index may be int64 (declared) or int32 (JAX x64 off). For int64 data of
// values < 2^31, every odd 32-bit word is zero.
__global__ void detect_kernel(const unsigned int* __restrict__ ei, int* __restrict__ flag) {
    unsigned int v = ei[(threadIdx.x << 1) + 1];
    unsigned long long b = __ballot(v != 0u);
    if (threadIdx.x == 0) *flag = (b != 0ull) ? 1 : 0;   // 1 => int32 layout
}

__device__ __forceinline__ int load_col(const void* ei, int i, int E, int f) {
    return f ? ((const int*)ei)[E + i] : (int)((const long long*)ei)[E + i];
}
__device__ __forceinline__ int load_row(const void* ei, int i, int E, int f) {
    return f ? ((const int*)ei)[i] : (int)((const long long*)ei)[i];
}

// ---------------------------------------------------------------- preprocessing
// one u64 atomic per edge: high32 = count, low32 = sum(w) in 2^-20 fixed point.
// Returned old count == this edge's rank within its destination bucket.
// 4 edges/thread for atomic-latency ILP.
__global__ void hist2_kernel(const void* __restrict__ ei, const float* __restrict__ w,
                             u64* __restrict__ packed, u32* __restrict__ rank,
                             const int* __restrict__ flag, int E) {
    int i0 = (blockIdx.x * blockDim.x + threadIdx.x) * 4;
    if (i0 >= E) return;
    int f = *flag;
    u32 rk[4];
#pragma unroll
    for (int k = 0; k < 4; k++) {
        int i = i0 + k;
        if (i < E) {
            int c = load_col(ei, i, E, f);
            u32 wq = __float2uint_rn(w[i] * 1048576.0f);     // 2^20 scale
            u64 old = atomicAdd(&packed[c], (1ull << 32) | (u64)wq);
            rk[k] = (u32)(old >> 32);
        }
    }
#pragma unroll
    for (int k = 0; k < 4; k++)
        if (i0 + k < E) rank[i0 + k] = rk[k];
}

// ---------------------------------------------------------------- scan (3-phase)
// scan1 fused with dinv/count unpack from the packed histogram.
__global__ __launch_bounds__(256) void scan1_kernel(const u64* __restrict__ packed,
                                                    float* __restrict__ dinv,
                                                    int* __restrict__ starts,
                                                    int* __restrict__ bsum, int n) {
    __shared__ int s[256];
    int i = blockIdx.x * 256 + threadIdx.x;
    int v = 0;
    if (i < n) {
        u64 p = packed[i];
        float wsum = (float)(u32)(p & 0xffffffffull) * (1.0f / 1048576.0f);
        dinv[i] = rsqrtf(1.0f + wsum);                   // self-loop weight 1 => deg >= 1
        v = (int)(p >> 32);
    }
    s[threadIdx.x] = v;
    __syncthreads();
#pragma unroll
    for (int d = 1; d < 256; d <<= 1) {
        int t = (threadIdx.x >= d) ? s[threadIdx.x - d] : 0;
        __syncthreads();
        s[threadIdx.x] += t;
        __syncthreads();
    }
    if (i < n) starts[i] = s[threadIdx.x] - v;   // exclusive
    if (threadIdx.x == 255) bsum[blockIdx.x] = s[255];
}

__global__ __launch_bounds__(256) void scan2_kernel(int* __restrict__ bsum, int nb) {
    __shared__ int s[256];
    int t = threadIdx.x;
    int v = (t < nb) ? bsum[t] : 0;
    s[t] = v;
    __syncthreads();
#pragma unroll
    for (int d = 1; d < 256; d <<= 1) {
        int u = (t >= d) ? s[t - d] : 0;
        __syncthreads();
        s[t] += u;
        __syncthreads();
    }
    if (t < nb) bsum[t] = s[t] - v;   // exclusive block offsets, in place
}

__global__ void scan3_kernel(int* __restrict__ starts, const int* __restrict__ boff,
                             int n, int E) {
    int i = blockIdx.x * blockDim.x + threadIdx.x;
    if (i == 0) starts[n] = E;   // sentinel
    if (i < n) starts[i] += boff[blockIdx.x];
}

// ---------------------------------------------------------------- CSR scatter (atomic-free)
// pairs[pos] = {src (low32), norm (high32)} grouped by destination.
// 4 edges/thread for load-chain ILP.
__global__ void scatter2_kernel(const void* __restrict__ ei, const float* __restrict__ w,
                                const float* __restrict__ dinv, const int* __restrict__ starts,
                                const u32* __restrict__ rank, u64* __restrict__ pairs,
                                const int* __restrict__ flag, int E) {
    int i0 = (blockIdx.x * blockDim.x + threadIdx.x) * 4;
    if (i0 >= E) return;
    int f = *flag;
    int r[4], c[4];
#pragma unroll
    for (int k = 0; k < 4; k++) {
        int i = i0 + k;
        if (i < E) { r[k] = load_row(ei, i, E, f); c[k] = load_col(ei, i, E, f); }
    }
#pragma unroll
    for (int k = 0; k < 4; k++) {
        int i = i0 + k;
        if (i < E) {
            float nm = dinv[r[k]] * w[i] * dinv[c[k]];
            int pos = starts[c[k]] + (int)rank[i];
            pairs[pos] = ((u64)__float_as_uint(nm) << 32) | (u32)r[k];
        }
    }
}

// ---------------------------------------------------------------- fp32 -> bf16 convert
__global__ void cvt_kernel(const float* __restrict__ x, const float* __restrict__ hidden,
                           unsigned short* __restrict__ xb, unsigned short* __restrict__ hb,
                           int nx, int nh) {
    int i4 = (blockIdx.x * blockDim.x + threadIdx.x) * 4;
    if (i4 < nx) {
        float4 v = *(const float4*)&x[i4];
        ushort4 o = { f2bf(v.x), f2bf(v.y), f2bf(v.z), f2bf(v.w) };
        *(ushort4*)&xb[i4] = o;
    } else {
        int j = i4 - nx;
        if (j < nh) {
            float4 v = *(const float4*)&hidden[j];
            ushort4 o = { f2bf(v.x), f2bf(v.y), f2bf(v.z), f2bf(v.w) };
            *(ushort4*)&hb[j] = o;
        }
    }
}

// ---------------------------------------------------------------- weight pack (k-major bf16)
__global__ void packW_kernel(const float* __restrict__ Wz, const float* __restrict__ Wr,
                             const float* __restrict__ Wh,
                             unsigned short* __restrict__ Bzrt, unsigned short* __restrict__ Wht) {
    int i = blockIdx.x * blockDim.x + threadIdx.x;
    if (i >= 192 * CAT_CH) return;
    int col = i / CAT_CH, k = i % CAT_CH;
    if (col < 128) {
        float v = (col < 64) ? Wz[k * 64 + col] : Wr[k * 64 + (col - 64)];
        Bzrt[col * CAT_CH + k] = f2bf(v);
    } else {
        Wht[(col - 128) * CAT_CH + k] = f2bf(Wh[k * 64 + (col - 128)]);
    }
}

// ---------------------------------------------------------------- bf16 MFMA GEMM
// C[M][TN] = [A0 | A1]([M][a0w] ++ [M][a1w], K=192 bf16) @ Bt([TN][192] bf16)
// FP8OUT: C stored as OCP e4m3 bytes; else bf16. Row-major either way.
// 256 threads = 4 waves; block tile 128 rows; wave owns 32 rows x TN cols.
template <int TN, bool FP8OUT>
__global__ __launch_bounds__(256) void gemm_bf16_kernel(
    const unsigned short* __restrict__ A0, int a0w,
    const unsigned short* __restrict__ A1, int a1w,
    const unsigned short* __restrict__ Bt,
    void* __restrict__ Cout, int nrows)
{
    __shared__ unsigned short As[128][48];    // 32 k + 16 pad
    __shared__ unsigned short Bs[TN][200];    // 192 k + 8 pad

    const int t = threadIdx.x, lane = t & 63, wave = t >> 6;
    const int rowBase = blockIdx.x * 128;

    for (int idx = t * 8; idx < TN * CAT_CH; idx += 256 * 8) {
        int col = idx / CAT_CH, k = idx % CAT_CH;
        *(int4*)&Bs[col][k] = *(const int4*)&Bt[idx];
    }

    f32x4 acc[2][TN / 16];
#pragma unroll
    for (int rf = 0; rf < 2; rf++)
#pragma unroll
        for (int cf = 0; cf < TN / 16; cf++) acc[rf][cf] = (f32x4){0.f, 0.f, 0.f, 0.f};

    const int srow = t >> 1, half = t & 1;     // A staging: 2 threads/row, 32B each
    int arow = rowBase + srow;
    if (arow >= nrows) arow = nrows - 1;

    for (int k0 = 0; k0 < CAT_CH; k0 += 32) {
        __syncthreads();
        {
            const unsigned short* src = (k0 < a0w)
                ? A0 + (size_t)arow * a0w + k0
                : A1 + (size_t)arow * a1w + (k0 - a0w);
            *(int4*)&As[srow][half * 16] = *(const int4*)(src + half * 16);
            *(int4*)&As[srow][half * 16 + 8] = *(const int4*)(src + half * 16 + 8);
        }
        __syncthreads();

        const int rbase = wave * 32;
        const int koff = (lane >> 4) * 8;
        bf16x8 a0 = *(const bf16x8*)&As[rbase + (lane & 15)][koff];
        bf16x8 a1 = *(const bf16x8*)&As[rbase + 16 + (lane & 15)][koff];
#pragma unroll
        for (int cf = 0; cf < TN / 16; cf++) {
            bf16x8 b = *(const bf16x8*)&Bs[cf * 16 + (lane & 15)][k0 + koff];
            acc[0][cf] = __builtin_amdgcn_mfma_f32_16x16x32_bf16(a0, b, acc[0][cf], 0, 0, 0);
            acc[1][cf] = __builtin_amdgcn_mfma_f32_16x16x32_bf16(a1, b, acc[1][cf], 0, 0, 0);
        }
    }

#pragma unroll
    for (int rf = 0; rf < 2; rf++)
#pragma unroll
        for (int cf = 0; cf < TN / 16; cf++) {
            int row0 = rowBase + wave * 32 + rf * 16 + (lane >> 4) * 4;
            int col  = cf * 16 + (lane & 15);
#pragma unroll
            for (int r = 0; r < 4; r++) {
                int row = row0 + r;
                if (row < nrows) {
                    if (FP8OUT)
                        ((unsigned char*)Cout)[(size_t)row * TN + col] = f2e4m3(acc[rf][cf][r]);
                    else
                        ((unsigned short*)Cout)[(size_t)row * TN + col] = f2bf(acc[rf][cf][r]);
                }
            }
        }
}

// ---------------------------------------------------------------- SpMM (CSR gather)
// One wave per node, 128 ch of fp8 Hzr8 (2 ch/lane), 8-deep pipelined gather,
// fused z/r epilogue.
__global__ __launch_bounds__(256) void spmm_zr_kernel(
    const unsigned char* __restrict__ H8, const u64* __restrict__ pairs,
    const int* __restrict__ starts, const float* __restrict__ dinv,
    const float* __restrict__ hidden, const float* __restrict__ bz,
    const float* __restrict__ br, float* __restrict__ Z,
    unsigned short* __restrict__ RHb, int N)
{
    int node = (blockIdx.x * 256 + threadIdx.x) >> 6;
    if (node >= N) return;
    int lane = threadIdx.x & 63;
    int s = starts[node], e = starts[node + 1];
    float d = dinv[node], d2 = d * d;
    const int ch = lane * 2;

    u32 self = *(const unsigned short*)&H8[(size_t)node * 128 + ch];
    f32x2 sv = e4m3x2_to_f(self);
    float ax = sv.x * d2, ay = sv.y * d2;

    for (int j = s; j < e; j += 8) {
        u32 hv[8]; float nm[8];
#pragma unroll
        for (int k = 0; k < 8; k++) {
            int jj = j + k;
            u64 p = pairs[(jj < e) ? jj : (e - 1)];   // clamp dup -> cache hit
            nm[k] = (jj < e) ? __uint_as_float((u32)(p >> 32)) : 0.f;
            hv[k] = *(const unsigned short*)&H8[(size_t)(u32)p * 128 + ch];
        }
#pragma unroll
        for (int k = 0; k < 8; k++) {
            f32x2 hf = e4m3x2_to_f(hv[k]);
            ax = fmaf(hf.x, nm[k], ax);
            ay = fmaf(hf.y, nm[k], ay);
        }
    }

    if (lane < 32) {
        int c = ch;                                 // z channels 0..62
        float2 o = { sigmoidf_(ax + bz[c]), sigmoidf_(ay + bz[c + 1]) };
        *(float2*)&Z[(size_t)node * 64 + c] = o;
    } else {
        int c = ch - 64;                            // r channels 0..62
        const float* hid = hidden + (size_t)node * 64 + c;
        float rh0 = sigmoidf_(ax + br[c])     * hid[0];
        float rh1 = sigmoidf_(ay + br[c + 1]) * hid[1];
        u32 packed = (u32)f2bf(rh0) | ((u32)f2bf(rh1) << 16);
        *(u32*)&RHb[(size_t)node * 64 + c] = packed;
    }
}

// One wave per node, 64 ch of bf16 Hhb, 8-deep pipelined gather,
// fused tanh + GRU blend -> out
__global__ __launch_bounds__(256) void spmm_h_kernel(
    const unsigned short* __restrict__ H, const u64* __restrict__ pairs,
    const int* __restrict__ starts, const float* __restrict__ dinv,
    const float* __restrict__ hidden, const float* __restrict__ bh,
    const float* __restrict__ Z, float* __restrict__ out, int N)
{
    int node = (blockIdx.x * 256 + threadIdx.x) >> 6;
    if (node >= N) return;
    int lane = threadIdx.x & 63;
    int s = starts[node], e = starts[node + 1];
    float d = dinv[node], d2 = d * d;

    float acc = bf1(H[(size_t)node * 64 + lane]) * d2;

    for (int j = s; j < e; j += 8) {
        unsigned short hv[8]; float nm[8];
#pragma unroll
        for (int k = 0; k < 8; k++) {
            int jj = j + k;
            u64 p = pairs[(jj < e) ? jj : (e - 1)];
            nm[k] = (jj < e) ? __uint_as_float((u32)(p >> 32)) : 0.f;
            hv[k] = H[(size_t)(u32)p * 64 + lane];
        }
#pragma unroll
        for (int k = 0; k < 8; k++)
            acc = fmaf(bf1(hv[k]), nm[k], acc);
    }

    size_t idx = (size_t)node * 64 + lane;
    float hc = tanhf(acc + bh[lane]);
    float z  = Z[idx];
    out[idx] = z * hidden[idx] + (1.f - z) * hc;
}

// ---------------------------------------------------------------- launcher
extern "C" void kernel_launch(void* const* d_in, const int* in_sizes, int n_in,
                              void* d_out, int out_size, void* d_ws, size_t ws_size,
                              hipStream_t stream) {
    const float* x      = (const float*)d_in[0];
    const void*  eidx   = d_in[1];
    const float* ew     = (const float*)d_in[2];
    const float* hidden = (const float*)d_in[3];
    const float* Wz     = (const float*)d_in[4];
    const float* bz     = (const float*)d_in[5];
    const float* Wr     = (const float*)d_in[6];
    const float* br     = (const float*)d_in[7];
    const float* Wh     = (const float*)d_in[8];
    const float* bh     = (const float*)d_in[9];
    float* out = (float*)d_out;

    const int E = in_sizes[2];            // 800000
    const int N = in_sizes[3] / OUT_CH;   // 50000

    // workspace carve-up (256B aligned)
    char* base = (char*)d_ws;
    size_t off = 0;
    auto carve = [&](size_t bytes) -> char* {
        char* p = base + off;
        off = (off + bytes + 255) & ~(size_t)255;
        return p;
    };
    u64*   packed = (u64*)  carve((size_t)N * 8);
    u32*   rank   = (u32*)  carve((size_t)E * 4);
    float* dinv   = (float*)carve((size_t)N * 4);
    int*   starts = (int*)  carve((size_t)(N + 1) * 4);
    int*   bsum   = (int*)  carve(256 * 4);
    u64*   pairs  = (u64*)  carve((size_t)E * 8);
    unsigned short* xb   = (unsigned short*)carve((size_t)N * 128 * 2);
    unsigned short* hb   = (unsigned short*)carve((size_t)N * 64 * 2);
    unsigned char*  Hzr8 = (unsigned char*)carve((size_t)N * 128);       // fp8 e4m3
    unsigned short* RHb  = (unsigned short*)carve((size_t)N * 64 * 2);
    unsigned short* Hhb  = (unsigned short*)carve((size_t)N * 64 * 2);
    float* Z = (float*)carve((size_t)N * 64 * 4);
    unsigned short* Bzrt = (unsigned short*)carve((size_t)128 * CAT_CH * 2);
    unsigned short* Wht  = (unsigned short*)carve((size_t)64 * CAT_CH * 2);
    int* flag = (int*)carve(4);
    if (off > ws_size) return;

    const int B256 = 256;
    const int gE4 = (E + 1023) / 1024;        // 4 edges/thread kernels
    const int gN = (N + B256 - 1) / B256;     // scan blocking (<=256 blocks)
    const int gM = (N + 127) / 128;           // GEMM row tiles
    const int gW = (N + 3) / 4;               // one wave per node

    // 1. dtype detect
    hipLaunchKernelGGL(detect_kernel, dim3(1), dim3(64), 0, stream,
                       (const unsigned int*)eidx, flag);

    // 2. packed histogram (count | sum w) + per-edge rank
    hipMemsetAsync(packed, 0, (size_t)N * 8, stream);
    hipLaunchKernelGGL(hist2_kernel, dim3(gE4), dim3(B256), 0, stream,
                       eidx, ew, packed, rank, flag, E);

    // 3. exclusive scan -> starts (fused dinv/count unpack)
    hipLaunchKernelGGL(scan1_kernel, dim3(gN), dim3(B256), 0, stream,
                       packed, dinv, starts, bsum, N);
    hipLaunchKernelGGL(scan2_kernel, dim3(1), dim3(B256), 0, stream, bsum, gN);
    hipLaunchKernelGGL(scan3_kernel, dim3(gN), dim3(B256), 0, stream, starts, bsum, N, E);

    // 4. atomic-free CSR scatter
    hipLaunchKernelGGL(scatter2_kernel, dim3(gE4), dim3(B256), 0, stream,
                       eidx, ew, dinv, starts, rank, pairs, flag, E);

    // 5. bf16 conversions + weight packs
    hipLaunchKernelGGL(cvt_kernel, dim3((N * CAT_CH / 4 + 255) / 256), dim3(B256), 0, stream,
                       x, hidden, xb, hb, N * 128, N * 64);
    hipLaunchKernelGGL(packW_kernel, dim3((192 * CAT_CH + 255) / 256), dim3(B256), 0, stream,
                       Wz, Wr, Wh, Bzrt, Wht);

    // 6. GEMM1: Hzr8(fp8) = [xb|hb] @ [Wz|Wr]
    hipLaunchKernelGGL((gemm_bf16_kernel<128, true>), dim3(gM), dim3(B256), 0, stream,
                       xb, 128, hb, 64, Bzrt, (void*)Hzr8, N);

    // 7. z/r aggregation (fp8 gather) + sigmoid epilogue -> Z, RHb
    hipLaunchKernelGGL(spmm_zr_kernel, dim3(gW), dim3(B256), 0, stream,
                       Hzr8, pairs, starts, dinv, hidden, bz, br, Z, RHb, N);

    // 8. GEMM2: Hhb(bf16) = [xb|RHb] @ Wh
    hipLaunchKernelGGL((gemm_bf16_kernel<64, false>), dim3(gM), dim3(B256), 0, stream,
                       xb, 128, RHb, 64, Wht, (void*)Hhb, N);

    // 9. h-candidate aggregation + tanh/GRU blend -> out
    hipLaunchKernelGGL(spmm_h_kernel, dim3(gW), dim3(B256), 0, stream,
                       Hhb, pairs, starts, dinv, hidden, bh, Z, out, N);
}

// Round 8
// 178.748 us; speedup vs baseline: 1.7074x; 1.1191x over previous
//
#include <hip/hip_runtime.h>
#include <hip/hip_bf16.h>
#include <cstdint>
#include <cstddef>

// ---------------------------------------------------------------- constants
#define IN_CH   128
#define OUT_CH  64
#define CAT_CH  192   // IN_CH + OUT_CH

typedef short bf16x8 __attribute__((ext_vector_type(8)));
typedef float f32x4  __attribute__((ext_vector_type(4)));
typedef float f32x2  __attribute__((ext_vector_type(2)));
typedef unsigned long long u64;
typedef unsigned int u32;

__device__ __forceinline__ float sigmoidf_(float x) { return 1.f / (1.f + __expf(-x)); }

// fp32 -> bf16 (RNE)
__device__ __forceinline__ unsigned short f2bf(float f) {
    u32 u = __float_as_uint(f);
    u32 r = (u + 0x7fffu + ((u >> 16) & 1u)) >> 16;
    return (unsigned short)r;
}
__device__ __forceinline__ float bflo(u32 v) { return __uint_as_float(v << 16); }
__device__ __forceinline__ float bfhi(u32 v) { return __uint_as_float(v & 0xffff0000u); }

// fp8 OCP e4m3 (gfx950 native converts)
__device__ __forceinline__ unsigned char f2e4m3(float f) {
    u32 p = __builtin_amdgcn_cvt_pk_fp8_f32(f, f, 0, false);
    return (unsigned char)p;
}
// 2 fp8 -> 2 f32; HI selects low/high half-word (builtin needs a constant)
template <bool HI>
__device__ __forceinline__ f32x2 fp8pk(u32 v) {
    return __builtin_amdgcn_cvt_pk_f32_fp8((int)v, HI);
}

// ---------------------------------------------------------------- dtype detect
// edge_index may be int64 (declared) or int32 (JAX x64 off). For int64 data of
// values < 2^31, every odd 32-bit word is zero.
__global__ void detect_kernel(const unsigned int* __restrict__ ei, int* __restrict__ flag) {
    unsigned int v = ei[(threadIdx.x << 1) + 1];
    unsigned long long b = __ballot(v != 0u);
    if (threadIdx.x == 0) *flag = (b != 0ull) ? 1 : 0;   // 1 => int32 layout
}

__device__ __forceinline__ int load_col(const void* ei, int i, int E, int f) {
    return f ? ((const int*)ei)[E + i] : (int)((const long long*)ei)[E + i];
}
__device__ __forceinline__ int load_row(const void* ei, int i, int E, int f) {
    return f ? ((const int*)ei)[i] : (int)((const long long*)ei)[i];
}

// ---------------------------------------------------------------- preprocessing
// one u64 atomic per edge: high32 = count, low32 = sum(w) in 2^-20 fixed point.
// Returned old count == this edge's rank within its destination bucket.
// 4 edges/thread for atomic-latency ILP.
__global__ void hist2_kernel(const void* __restrict__ ei, const float* __restrict__ w,
                             u64* __restrict__ packed, u32* __restrict__ rank,
                             const int* __restrict__ flag, int E) {
    int i0 = (blockIdx.x * blockDim.x + threadIdx.x) * 4;
    if (i0 >= E) return;
    int f = *flag;
    u32 rk[4];
#pragma unroll
    for (int k = 0; k < 4; k++) {
        int i = i0 + k;
        if (i < E) {
            int c = load_col(ei, i, E, f);
            u32 wq = __float2uint_rn(w[i] * 1048576.0f);     // 2^20 scale
            u64 old = atomicAdd(&packed[c], (1ull << 32) | (u64)wq);
            rk[k] = (u32)(old >> 32);
        }
    }
#pragma unroll
    for (int k = 0; k < 4; k++)
        if (i0 + k < E) rank[i0 + k] = rk[k];
}

// ---------------------------------------------------------------- scan (3-phase)
// scan1 fused with dinv/count unpack from the packed histogram.
__global__ __launch_bounds__(256) void scan1_kernel(const u64* __restrict__ packed,
                                                    float* __restrict__ dinv,
                                                    int* __restrict__ starts,
                                                    int* __restrict__ bsum, int n) {
    __shared__ int s[256];
    int i = blockIdx.x * 256 + threadIdx.x;
    int v = 0;
    if (i < n) {
        u64 p = packed[i];
        float wsum = (float)(u32)(p & 0xffffffffull) * (1.0f / 1048576.0f);
        dinv[i] = rsqrtf(1.0f + wsum);                   // self-loop weight 1 => deg >= 1
        v = (int)(p >> 32);
    }
    s[threadIdx.x] = v;
    __syncthreads();
#pragma unroll
    for (int d = 1; d < 256; d <<= 1) {
        int t = (threadIdx.x >= d) ? s[threadIdx.x - d] : 0;
        __syncthreads();
        s[threadIdx.x] += t;
        __syncthreads();
    }
    if (i < n) starts[i] = s[threadIdx.x] - v;   // exclusive
    if (threadIdx.x == 255) bsum[blockIdx.x] = s[255];
}

__global__ __launch_bounds__(256) void scan2_kernel(int* __restrict__ bsum, int nb) {
    __shared__ int s[256];
    int t = threadIdx.x;
    int v = (t < nb) ? bsum[t] : 0;
    s[t] = v;
    __syncthreads();
#pragma unroll
    for (int d = 1; d < 256; d <<= 1) {
        int u = (t >= d) ? s[t - d] : 0;
        __syncthreads();
        s[t] += u;
        __syncthreads();
    }
    if (t < nb) bsum[t] = s[t] - v;   // exclusive block offsets, in place
}

__global__ void scan3_kernel(int* __restrict__ starts, const int* __restrict__ boff,
                             int n, int E) {
    int i = blockIdx.x * blockDim.x + threadIdx.x;
    if (i == 0) starts[n] = E;   // sentinel
    if (i < n) starts[i] += boff[blockIdx.x];
}

// ---------------------------------------------------------------- CSR scatter (atomic-free)
// pairs[pos] = {src*128 byte-offset (low32), norm (high32)} grouped by dest.
// Both gather tables (fp8 128ch, bf16 64ch) have 128-byte rows.
// 4 edges/thread for load-chain ILP.
__global__ void scatter2_kernel(const void* __restrict__ ei, const float* __restrict__ w,
                                const float* __restrict__ dinv, const int* __restrict__ starts,
                                const u32* __restrict__ rank, u64* __restrict__ pairs,
                                const int* __restrict__ flag, int E) {
    int i0 = (blockIdx.x * blockDim.x + threadIdx.x) * 4;
    if (i0 >= E) return;
    int f = *flag;
    int r[4], c[4];
#pragma unroll
    for (int k = 0; k < 4; k++) {
        int i = i0 + k;
        if (i < E) { r[k] = load_row(ei, i, E, f); c[k] = load_col(ei, i, E, f); }
    }
#pragma unroll
    for (int k = 0; k < 4; k++) {
        int i = i0 + k;
        if (i < E) {
            float nm = dinv[r[k]] * w[i] * dinv[c[k]];
            int pos = starts[c[k]] + (int)rank[i];
            pairs[pos] = ((u64)__float_as_uint(nm) << 32) | (u32)(r[k] << 7);
        }
    }
}

// ---------------------------------------------------------------- fp32 -> bf16 convert
__global__ void cvt_kernel(const float* __restrict__ x, const float* __restrict__ hidden,
                           unsigned short* __restrict__ xb, unsigned short* __restrict__ hb,
                           int nx, int nh) {
    int i4 = (blockIdx.x * blockDim.x + threadIdx.x) * 4;
    if (i4 < nx) {
        float4 v = *(const float4*)&x[i4];
        ushort4 o = { f2bf(v.x), f2bf(v.y), f2bf(v.z), f2bf(v.w) };
        *(ushort4*)&xb[i4] = o;
    } else {
        int j = i4 - nx;
        if (j < nh) {
            float4 v = *(const float4*)&hidden[j];
            ushort4 o = { f2bf(v.x), f2bf(v.y), f2bf(v.z), f2bf(v.w) };
            *(ushort4*)&hb[j] = o;
        }
    }
}

// ---------------------------------------------------------------- weight pack (k-major bf16)
__global__ void packW_kernel(const float* __restrict__ Wz, const float* __restrict__ Wr,
                             const float* __restrict__ Wh,
                             unsigned short* __restrict__ Bzrt, unsigned short* __restrict__ Wht) {
    int i = blockIdx.x * blockDim.x + threadIdx.x;
    if (i >= 192 * CAT_CH) return;
    int col = i / CAT_CH, k = i % CAT_CH;
    if (col < 128) {
        float v = (col < 64) ? Wz[k * 64 + col] : Wr[k * 64 + (col - 64)];
        Bzrt[col * CAT_CH + k] = f2bf(v);
    } else {
        Wht[(col - 128) * CAT_CH + k] = f2bf(Wh[k * 64 + (col - 128)]);
    }
}

// ---------------------------------------------------------------- bf16 MFMA GEMM
// C[M][TN] = [A0 | A1]([M][a0w] ++ [M][a1w], K=192 bf16) @ Bt([TN][192] bf16)
// FP8OUT: C stored as OCP e4m3 bytes; else bf16. Row-major either way.
template <int TN, bool FP8OUT>
__global__ __launch_bounds__(256) void gemm_bf16_kernel(
    const unsigned short* __restrict__ A0, int a0w,
    const unsigned short* __restrict__ A1, int a1w,
    const unsigned short* __restrict__ Bt,
    void* __restrict__ Cout, int nrows)
{
    __shared__ unsigned short As[128][48];    // 32 k + 16 pad
    __shared__ unsigned short Bs[TN][200];    // 192 k + 8 pad

    const int t = threadIdx.x, lane = t & 63, wave = t >> 6;
    const int rowBase = blockIdx.x * 128;

    for (int idx = t * 8; idx < TN * CAT_CH; idx += 256 * 8) {
        int col = idx / CAT_CH, k = idx % CAT_CH;
        *(int4*)&Bs[col][k] = *(const int4*)&Bt[idx];
    }

    f32x4 acc[2][TN / 16];
#pragma unroll
    for (int rf = 0; rf < 2; rf++)
#pragma unroll
        for (int cf = 0; cf < TN / 16; cf++) acc[rf][cf] = (f32x4){0.f, 0.f, 0.f, 0.f};

    const int srow = t >> 1, half = t & 1;     // A staging: 2 threads/row, 32B each
    int arow = rowBase + srow;
    if (arow >= nrows) arow = nrows - 1;

    for (int k0 = 0; k0 < CAT_CH; k0 += 32) {
        __syncthreads();
        {
            const unsigned short* src = (k0 < a0w)
                ? A0 + (size_t)arow * a0w + k0
                : A1 + (size_t)arow * a1w + (k0 - a0w);
            *(int4*)&As[srow][half * 16] = *(const int4*)(src + half * 16);
            *(int4*)&As[srow][half * 16 + 8] = *(const int4*)(src + half * 16 + 8);
        }
        __syncthreads();

        const int rbase = wave * 32;
        const int koff = (lane >> 4) * 8;
        bf16x8 a0 = *(const bf16x8*)&As[rbase + (lane & 15)][koff];
        bf16x8 a1 = *(const bf16x8*)&As[rbase + 16 + (lane & 15)][koff];
#pragma unroll
        for (int cf = 0; cf < TN / 16; cf++) {
            bf16x8 b = *(const bf16x8*)&Bs[cf * 16 + (lane & 15)][k0 + koff];
            acc[0][cf] = __builtin_amdgcn_mfma_f32_16x16x32_bf16(a0, b, acc[0][cf], 0, 0, 0);
            acc[1][cf] = __builtin_amdgcn_mfma_f32_16x16x32_bf16(a1, b, acc[1][cf], 0, 0, 0);
        }
    }

#pragma unroll
    for (int rf = 0; rf < 2; rf++)
#pragma unroll
        for (int cf = 0; cf < TN / 16; cf++) {
            int row0 = rowBase + wave * 32 + rf * 16 + (lane >> 4) * 4;
            int col  = cf * 16 + (lane & 15);
#pragma unroll
            for (int r = 0; r < 4; r++) {
                int row = row0 + r;
                if (row < nrows) {
                    if (FP8OUT)
                        ((unsigned char*)Cout)[(size_t)row * TN + col] = f2e4m3(acc[rf][cf][r]);
                    else
                        ((unsigned short*)Cout)[(size_t)row * TN + col] = f2bf(acc[rf][cf][r]);
                }
            }
        }
}

// ---------------------------------------------------------------- SpMM (CSR gather)
// One wave per node; 32 lanes x 4B per edge, TWO edges per wave-instruction
// (half = lane>>5 picks the edge). 16 edges in flight per iteration.
// fp8 table, 128 ch; sub = lane&31 owns channels 4*sub..4*sub+3.
__global__ __launch_bounds__(256) void spmm_zr_kernel(
    const unsigned char* __restrict__ H8, const u64* __restrict__ pairs,
    const int* __restrict__ starts, const float* __restrict__ dinv,
    const float* __restrict__ hidden, const float* __restrict__ bz,
    const float* __restrict__ br, float* __restrict__ Z,
    unsigned short* __restrict__ RHb, int N)
{
    int node = (blockIdx.x * 256 + threadIdx.x) >> 6;
    if (node >= N) return;
    const int lane = threadIdx.x & 63;
    const int sub = lane & 31, half = lane >> 5;
    int s = starts[node], e = starts[node + 1];
    float d = dinv[node], d2 = d * d;

    float a0 = 0.f, a1 = 0.f, a2 = 0.f, a3 = 0.f;
    if (half == 0) {   // self-loop term on half 0
        u32 sv = *(const u32*)&H8[(size_t)node * 128 + sub * 4];
        f32x2 s01 = fp8pk<false>(sv), s23 = fp8pk<true>(sv);
        a0 = s01.x * d2; a1 = s01.y * d2; a2 = s23.x * d2; a3 = s23.y * d2;
    }

    int j = s;
    int full = s + ((e - s) & ~15);
    for (; j < full; j += 16) {        // select-free main loop
        u32 hv[8]; float nm[8];
#pragma unroll
        for (int k = 0; k < 8; k++) {
            u64 p = pairs[j + k * 2 + half];
            nm[k] = __uint_as_float((u32)(p >> 32));
            hv[k] = *(const u32*)&H8[(size_t)(u32)p + sub * 4];
        }
#pragma unroll
        for (int k = 0; k < 8; k++) {
            f32x2 h01 = fp8pk<false>(hv[k]), h23 = fp8pk<true>(hv[k]);
            a0 = fmaf(h01.x, nm[k], a0); a1 = fmaf(h01.y, nm[k], a1);
            a2 = fmaf(h23.x, nm[k], a2); a3 = fmaf(h23.y, nm[k], a3);
        }
    }
    if (j < e) {                       // one clamped tail iteration
        u32 hv[8]; float nm[8];
#pragma unroll
        for (int k = 0; k < 8; k++) {
            int jj = j + k * 2 + half;
            u64 p = pairs[(jj < e) ? jj : (e - 1)];
            nm[k] = (jj < e) ? __uint_as_float((u32)(p >> 32)) : 0.f;
            hv[k] = *(const u32*)&H8[(size_t)(u32)p + sub * 4];
        }
#pragma unroll
        for (int k = 0; k < 8; k++) {
            f32x2 h01 = fp8pk<false>(hv[k]), h23 = fp8pk<true>(hv[k]);
            a0 = fmaf(h01.x, nm[k], a0); a1 = fmaf(h01.y, nm[k], a1);
            a2 = fmaf(h23.x, nm[k], a2); a3 = fmaf(h23.y, nm[k], a3);
        }
    }

    // fold the two edge-halves
    a0 += __shfl_xor(a0, 32, 64);
    a1 += __shfl_xor(a1, 32, 64);
    a2 += __shfl_xor(a2, 32, 64);
    a3 += __shfl_xor(a3, 32, 64);

    if (half == 0) {
        if (sub < 16) {                // z channels c = 4*sub .. +3
            int c = sub * 4;
            float4 b4 = *(const float4*)&bz[c];
            float4 o = { sigmoidf_(a0 + b4.x), sigmoidf_(a1 + b4.y),
                         sigmoidf_(a2 + b4.z), sigmoidf_(a3 + b4.w) };
            *(float4*)&Z[(size_t)node * 64 + c] = o;
        } else {                       // r channels c = 4*(sub-16) .. +3
            int c = (sub - 16) * 4;
            float4 b4 = *(const float4*)&br[c];
            float4 hid = *(const float4*)&hidden[(size_t)node * 64 + c];
            float r0 = sigmoidf_(a0 + b4.x) * hid.x;
            float r1 = sigmoidf_(a1 + b4.y) * hid.y;
            float r2 = sigmoidf_(a2 + b4.z) * hid.z;
            float r3 = sigmoidf_(a3 + b4.w) * hid.w;
            ushort4 o = { f2bf(r0), f2bf(r1), f2bf(r2), f2bf(r3) };
            *(ushort4*)&RHb[(size_t)node * 64 + c] = o;
        }
    }
}

// One wave per node; 32 lanes x 4B (2 bf16 ch) per edge, two edges per
// instruction. Fused tanh + GRU blend -> out.
__global__ __launch_bounds__(256) void spmm_h_kernel(
    const unsigned short* __restrict__ H, const u64* __restrict__ pairs,
    const int* __restrict__ starts, const float* __restrict__ dinv,
    const float* __restrict__ hidden, const float* __restrict__ bh,
    const float* __restrict__ Z, float* __restrict__ out, int N)
{
    int node = (blockIdx.x * 256 + threadIdx.x) >> 6;
    if (node >= N) return;
    const int lane = threadIdx.x & 63;
    const int sub = lane & 31, half = lane >> 5;
    const unsigned char* Hb = (const unsigned char*)H;
    int s = starts[node], e = starts[node + 1];
    float d = dinv[node], d2 = d * d;

    float ax = 0.f, ay = 0.f;
    if (half == 0) {
        u32 sv = *(const u32*)&Hb[(size_t)node * 128 + sub * 4];
        ax = bflo(sv) * d2; ay = bfhi(sv) * d2;
    }

    int j = s;
    int full = s + ((e - s) & ~15);
    for (; j < full; j += 16) {
        u32 hv[8]; float nm[8];
#pragma unroll
        for (int k = 0; k < 8; k++) {
            u64 p = pairs[j + k * 2 + half];
            nm[k] = __uint_as_float((u32)(p >> 32));
            hv[k] = *(const u32*)&Hb[(size_t)(u32)p + sub * 4];
        }
#pragma unroll
        for (int k = 0; k < 8; k++) {
            ax = fmaf(bflo(hv[k]), nm[k], ax);
            ay = fmaf(bfhi(hv[k]), nm[k], ay);
        }
    }
    if (j < e) {
        u32 hv[8]; float nm[8];
#pragma unroll
        for (int k = 0; k < 8; k++) {
            int jj = j + k * 2 + half;
            u64 p = pairs[(jj < e) ? jj : (e - 1)];
            nm[k] = (jj < e) ? __uint_as_float((u32)(p >> 32)) : 0.f;
            hv[k] = *(const u32*)&Hb[(size_t)(u32)p + sub * 4];
        }
#pragma unroll
        for (int k = 0; k < 8; k++) {
            ax = fmaf(bflo(hv[k]), nm[k], ax);
            ay = fmaf(bfhi(hv[k]), nm[k], ay);
        }
    }

    ax += __shfl_xor(ax, 32, 64);
    ay += __shfl_xor(ay, 32, 64);

    if (half == 0) {                  // channels c = 2*sub, 2*sub+1
        int c = sub * 2;
        size_t idx = (size_t)node * 64 + c;
        float2 hid = *(const float2*)&hidden[idx];
        float2 z   = *(const float2*)&Z[idx];
        float hc0 = tanhf(ax + bh[c]);
        float hc1 = tanhf(ay + bh[c + 1]);
        float2 o = { z.x * hid.x + (1.f - z.x) * hc0,
                     z.y * hid.y + (1.f - z.y) * hc1 };
        *(float2*)&out[idx] = o;
    }
}

// ---------------------------------------------------------------- launcher
extern "C" void kernel_launch(void* const* d_in, const int* in_sizes, int n_in,
                              void* d_out, int out_size, void* d_ws, size_t ws_size,
                              hipStream_t stream) {
    const float* x      = (const float*)d_in[0];
    const void*  eidx   = d_in[1];
    const float* ew     = (const float*)d_in[2];
    const float* hidden = (const float*)d_in[3];
    const float* Wz     = (const float*)d_in[4];
    const float* bz     = (const float*)d_in[5];
    const float* Wr     = (const float*)d_in[6];
    const float* br     = (const float*)d_in[7];
    const float* Wh     = (const float*)d_in[8];
    const float* bh     = (const float*)d_in[9];
    float* out = (float*)d_out;

    const int E = in_sizes[2];            // 800000
    const int N = in_sizes[3] / OUT_CH;   // 50000

    // workspace carve-up (256B aligned)
    char* base = (char*)d_ws;
    size_t off = 0;
    auto carve = [&](size_t bytes) -> char* {
        char* p = base + off;
        off = (off + bytes + 255) & ~(size_t)255;
        return p;
    };
    u64*   packed = (u64*)  carve((size_t)N * 8);
    u32*   rank   = (u32*)  carve((size_t)E * 4);
    float* dinv   = (float*)carve((size_t)N * 4);
    int*   starts = (int*)  carve((size_t)(N + 1) * 4);
    int*   bsum   = (int*)  carve(256 * 4);
    u64*   pairs  = (u64*)  carve((size_t)E * 8);
    unsigned short* xb   = (unsigned short*)carve((size_t)N * 128 * 2);
    unsigned short* hb   = (unsigned short*)carve((size_t)N * 64 * 2);
    unsigned char*  Hzr8 = (unsigned char*)carve((size_t)N * 128);       // fp8 e4m3
    unsigned short* RHb  = (unsigned short*)carve((size_t)N * 64 * 2);
    unsigned short* Hhb  = (unsigned short*)carve((size_t)N * 64 * 2);
    float* Z = (float*)carve((size_t)N * 64 * 4);
    unsigned short* Bzrt = (unsigned short*)carve((size_t)128 * CAT_CH * 2);
    unsigned short* Wht  = (unsigned short*)carve((size_t)64 * CAT_CH * 2);
    int* flag = (int*)carve(4);
    if (off > ws_size) return;

    const int B256 = 256;
    const int gE4 = (E + 1023) / 1024;        // 4 edges/thread kernels
    const int gN = (N + B256 - 1) / B256;     // scan blocking (<=256 blocks)
    const int gM = (N + 127) / 128;           // GEMM row tiles
    const int gW = (N + 3) / 4;               // one wave per node

    // 1. dtype detect
    hipLaunchKernelGGL(detect_kernel, dim3(1), dim3(64), 0, stream,
                       (const unsigned int*)eidx, flag);

    // 2. packed histogram (count | sum w) + per-edge rank
    (void)hipMemsetAsync(packed, 0, (size_t)N * 8, stream);
    hipLaunchKernelGGL(hist2_kernel, dim3(gE4), dim3(B256), 0, stream,
                       eidx, ew, packed, rank, flag, E);

    // 3. exclusive scan -> starts (fused dinv/count unpack)
    hipLaunchKernelGGL(scan1_kernel, dim3(gN), dim3(B256), 0, stream,
                       packed, dinv, starts, bsum, N);
    hipLaunchKernelGGL(scan2_kernel, dim3(1), dim3(B256), 0, stream, bsum, gN);
    hipLaunchKernelGGL(scan3_kernel, dim3(gN), dim3(B256), 0, stream, starts, bsum, N, E);

    // 4. atomic-free CSR scatter (byte offsets in pairs)
    hipLaunchKernelGGL(scatter2_kernel, dim3(gE4), dim3(B256), 0, stream,
                       eidx, ew, dinv, starts, rank, pairs, flag, E);

    // 5. bf16 conversions + weight packs
    hipLaunchKernelGGL(cvt_kernel, dim3((N * CAT_CH / 4 + 255) / 256), dim3(B256), 0, stream,
                       x, hidden, xb, hb, N * 128, N * 64);
    hipLaunchKernelGGL(packW_kernel, dim3((192 * CAT_CH + 255) / 256), dim3(B256), 0, stream,
                       Wz, Wr, Wh, Bzrt, Wht);

    // 6. GEMM1: Hzr8(fp8) = [xb|hb] @ [Wz|Wr]
    hipLaunchKernelGGL((gemm_bf16_kernel<128, true>), dim3(gM), dim3(B256), 0, stream,
                       xb, 128, hb, 64, Bzrt, (void*)Hzr8, N);

    // 7. z/r aggregation (fp8 gather, 2 edges/instr) -> Z, RHb
    hipLaunchKernelGGL(spmm_zr_kernel, dim3(gW), dim3(B256), 0, stream,
                       Hzr8, pairs, starts, dinv, hidden, bz, br, Z, RHb, N);

    // 8. GEMM2: Hhb(bf16) = [xb|RHb] @ Wh
    hipLaunchKernelGGL((gemm_bf16_kernel<64, false>), dim3(gM), dim3(B256), 0, stream,
                       xb, 128, RHb, 64, Wht, (void*)Hhb, N);

    // 9. h-candidate aggregation (2 edges/instr) + tanh/GRU blend -> out
    hipLaunchKernelGGL(spmm_h_kernel, dim3(gW), dim3(B256), 0, stream,
                       Hhb, pairs, starts, dinv, hidden, bh, Z, out, N);
}